// Round 18
// baseline (393.284 us; speedup 1.0000x reference)
//
#include <hip/hip_runtime.h>

typedef unsigned short ushort_t;
typedef __attribute__((ext_vector_type(8))) short short8;
typedef __attribute__((ext_vector_type(4))) float floatx4;
typedef __attribute__((ext_vector_type(4))) unsigned short ushort4v;

#define B_ 2
#define S_ 2048
#define D_ 1024
#define NH_ 16
#define HD_ 64
#define M_ 4096

// 0.125 (1/sqrt(hd)) * log2(e), folded into K at the QKV epilogue
#define KSCALE 0.18033688011112042f

__device__ __forceinline__ ushort_t f2bf(float f) {
    unsigned u = __builtin_bit_cast(unsigned, f);
    return (ushort_t)((u + 0x7FFFu + ((u >> 16) & 1u)) >> 16);
}

__device__ __forceinline__ void gload_lds16(const ushort_t* g, ushort_t* l) {
    __builtin_amdgcn_global_load_lds(
        (const __attribute__((address_space(1))) unsigned int*)(g),
        (__attribute__((address_space(3))) unsigned int*)(l), 16, 0, 0);
}

// ---------------------------------------------------------------- fat transpose: 256 src rows x 64 src cols
__device__ __forceinline__ void transpose_slab(
    const float* __restrict__ src, ushort_t* __restrict__ dst,
    int srs, int drs, int by, int bx, int tid, ushort_t* L) {
    const int tx = tid & 15, ty = tid >> 4;
    const float* s0 = src + (size_t)(by * 256 + ty * 4) * srs + bx * 64 + tx * 4;
    #pragma unroll
    for (int i = 0; i < 4; ++i) {
        float a[4][4];
        #pragma unroll
        for (int r = 0; r < 4; ++r) {
            float4 m = *(const float4*)(s0 + (size_t)(i * 64 + r) * srs);
            a[r][0] = m.x; a[r][1] = m.y; a[r][2] = m.z; a[r][3] = m.w;
        }
        const int p = i * 8 + (ty >> 1), plow = ty & 1;   // granule-pair index of g = i*16+ty
        #pragma unroll
        for (int j = 0; j < 4; ++j) {
            const int c = tx * 4 + j;                     // dst-local row (= src col)
            const int pp = p ^ tx;                        // 16B-unit swizzle, s(c) = c>>2 = tx
            ushort4v t;
            t[0] = f2bf(a[0][j]); t[1] = f2bf(a[1][j]);
            t[2] = f2bf(a[2][j]); t[3] = f2bf(a[3][j]);
            *(ushort4v*)&L[c * 256 + (pp * 2 + plow) * 4] = t;
        }
    }
    __syncthreads();
    const int k = tid & 31, cg = tid >> 5;
    #pragma unroll
    for (int it = 0; it < 8; ++it) {
        const int c = it * 8 + cg;
        const int pp = k ^ (c >> 2);                      // inverse of the write swizzle
        *(short8*)(dst + (size_t)(bx * 64 + c) * drs + by * 256 + k * 8) =
            *(const short8*)&L[c * 256 + pp * 8];
    }
}

// ---------------------------------------------------------------- LayerNorm (ddof=1): one row per WAVE, barrier-free
__device__ __forceinline__ void ln_row_wave(const float* __restrict__ x,
                                            const float* __restrict__ w,
                                            const float* __restrict__ b,
                                            ushort_t* __restrict__ out, int row, int l) {
    const float* xr = x + (size_t)row * D_;
    float4 v[4]; float s = 0.f, ss = 0.f;
    #pragma unroll
    for (int i = 0; i < 4; ++i) {
        v[i] = *(const float4*)(xr + (i * 64 + l) * 4);
        s += v[i].x + v[i].y + v[i].z + v[i].w;
        ss += v[i].x * v[i].x + v[i].y * v[i].y + v[i].z * v[i].z + v[i].w * v[i].w;
    }
    #pragma unroll
    for (int off = 32; off >= 1; off >>= 1) { s += __shfl_xor(s, off); ss += __shfl_xor(ss, off); }
    float mu = s * (1.f / D_);
    float var = (ss - (float)D_ * mu * mu) * (1.f / (D_ - 1));
    float rstd = rsqrtf(var + 1e-4f);
    #pragma unroll
    for (int i = 0; i < 4; ++i) {
        int d = (i * 64 + l) * 4;
        float4 wv = *(const float4*)(w + d);
        float4 bv = *(const float4*)(b + d);
        ushort4v o;
        o[0] = f2bf((v[i].x - mu) * rstd * wv.x + bv.x);
        o[1] = f2bf((v[i].y - mu) * rstd * wv.y + bv.y);
        o[2] = f2bf((v[i].z - mu) * rstd * wv.z + bv.z);
        o[3] = f2bf((v[i].w - mu) * rstd * wv.w + bv.w);
        *(ushort4v*)&out[(size_t)row * D_ + d] = o;
    }
}

__global__ __launch_bounds__(256) void ln4_kernel(const float* __restrict__ x,
                                                  const float* __restrict__ w,
                                                  const float* __restrict__ b,
                                                  ushort_t* __restrict__ out) {
    ln_row_wave(x, w, b, out, blockIdx.x * 4 + (threadIdx.x >> 6), threadIdx.x & 63);
}

// ---------------------------------------------------------------- fused prep: ALL transposes + wsum + LN1
__global__ __launch_bounds__(256) void prep_kernel(
    const float* __restrict__ W_qkv, const float* __restrict__ W1,
    const float* __restrict__ W2, const float* __restrict__ W_out,
    ushort_t* __restrict__ WqkvT, ushort_t* __restrict__ W1T,
    ushort_t* __restrict__ W2T, float* __restrict__ wsum,
    const float* __restrict__ x, const float* __restrict__ ln1_w,
    const float* __restrict__ ln1_b, ushort_t* __restrict__ ln1_out) {
    __shared__ __align__(16) ushort_t L[64 * 256];      // 32 KiB
    const int bid = blockIdx.x;
    const int tid = threadIdx.x;
    if (bid < 192) {                    // W_qkv [16][1024][192] -> WqkvT [16*192][1024]
        int bz = bid / 12, rem = bid % 12;
        transpose_slab(W_qkv + (size_t)bz * D_ * 192, WqkvT + (size_t)bz * 192 * D_,
                       192, D_, rem / 3, rem % 3, tid, L);
    } else if (bid < 448) {             // W1 [1024][4096] -> W1T [4096][1024]
        int r = bid - 192;
        transpose_slab(W1, W1T, M_, D_, r >> 6, r & 63, tid, L);
    } else if (bid < 704) {             // W2 [4096][1024] -> W2T [1024][4096]
        int r = bid - 448;
        transpose_slab(W2, W2T, D_, M_, r >> 4, r & 15, tid, L);
    } else if (bid < 712) {             // wsum over (n,h) of W_out, float4 lanes
        int cb = bid - 704;
        float4* part = (float4*)L;
        int tx = tid & 31, rg = tid >> 5;
        int col = cb * 128 + tx * 4;
        float4 s = {0.f, 0.f, 0.f, 0.f};
        for (int r = rg; r < NH_ * HD_; r += 8) {
            float4 v = *(const float4*)(W_out + (size_t)r * D_ + col);
            s.x += v.x; s.y += v.y; s.z += v.z; s.w += v.w;
        }
        part[tid] = s;
        __syncthreads();
        if (tid < 32) {
            float4 t = {0.f, 0.f, 0.f, 0.f};
            #pragma unroll
            for (int g = 0; g < 8; ++g) {
                float4 p = part[g * 32 + tid];
                t.x += p.x; t.y += p.y; t.z += p.z; t.w += p.w;
            }
            *(float4*)(wsum + cb * 128 + tid * 4) = t;
        }
    } else {                            // LN1: 4 rows per block, one per wave
        ln_row_wave(x, ln1_w, ln1_b, ln1_out, (bid - 712) * 4 + (tid >> 6), tid & 63);
    }
}

// ---------------------------------------------------------------- gather + residual (x1 only; d_out handled by mlp2_reduce)
__global__ __launch_bounds__(256) void gather_resid(
    const float* __restrict__ x, const float* __restrict__ attn,
    const float* __restrict__ wsum, float* __restrict__ x1) {
    __shared__ float tile[128][65];
    const int tid = threadIdx.x;
    const int dchunk = blockIdx.x;          // 8 chunks of 128 d
    const int stile = blockIdx.y;           // 64 tiles: b = stile>>5, shi = stile&31
    const int b = stile >> 5, shi = stile & 31;
    const int h = tid & 63;
    const int wv = tid >> 6;
    #pragma unroll
    for (int r = 0; r < 32; ++r) {
        int dloc = r * 4 + wv;
        int d = dchunk * 128 + dloc;
        int q = ((d & 63) << 5) + shi;
        tile[dloc][h] = attn[((size_t)(b * NH_ + (d >> 6)) * S_ + q) * HD_ + h];
    }
    __syncthreads();
    const int row0 = b * S_ + shi * 64;
    const int dcol = tid & 127;
    const int d = dchunk * 128 + dcol;
    const float wsd = wsum[d];
    #pragma unroll
    for (int r = 0; r < 32; ++r) {
        int sr = r * 2 + (tid >> 7);
        size_t idx = (size_t)(row0 + sr) * D_ + d;
        x1[idx] = x[idx] + wsd * tile[dcol][sr];
    }
}

// ---------------------------------------------------------------- MLP2 split-K reduce: out = x1 + b2 + sum_z part_z (z=2)
__global__ __launch_bounds__(256) void mlp2_reduce(
    const float* __restrict__ part, const float* __restrict__ x1,
    const float* __restrict__ b2, float* __restrict__ out) {
    int i = blockIdx.x * 256 + threadIdx.x;          // float4 index
    #pragma unroll
    for (int it = 0; it < 4; ++it, i += 1024 * 256) {
        size_t o = (size_t)i * 4;
        float4 s = *(const float4*)(x1 + o);
        float4 bb = *(const float4*)(b2 + ((i * 4) & (D_ - 1)));
        s.x += bb.x; s.y += bb.y; s.z += bb.z; s.w += bb.w;
        #pragma unroll
        for (int z = 0; z < 2; ++z) {
            float4 p = *(const float4*)(part + (size_t)z * ((size_t)B_ * S_ * D_) + o);
            s.x += p.x; s.y += p.y; s.z += p.z; s.w += p.w;
        }
        *(float4*)(out + o) = s;
    }
}

// ---------------------------------------------------------------- GEMM: C = A[M][K] * BT[N][K]^T
// Pipelined K-loop (counted vmcnt, never 0 mid-loop): LDS [slot][khalf][128][32] bf16,
// granule swizzle g^((r>>1)&3) (conflict-free b128 reads). Per phase: issue next-tile
// half stages -> vmcnt(8) -> barrier -> ds_read -> 16 MFMA. Progressive khalf retire
// makes the cross-slot overwrite race-free (overwritten khalf is barrier-retired).
// EPI 0: scatter Q/K to qkv (K pre-scaled), V packed to vT. EPI 1: fast-gelu bf16.
// EPI 4: split-K (blockIdx.z) plain fp32 partial store (reduced by mlp2_reduce).
template <int EPI>
__global__ __launch_bounds__(256) void gemm_bt(
    const ushort_t* __restrict__ A, const ushort_t* __restrict__ BT,
    int M, int N, int K, int ld, const float* __restrict__ bias,
    void* __restrict__ outp, void* __restrict__ outp2) {
    __shared__ __align__(16) ushort_t As[16384];   // [2 slot][2 khalf][128][32]
    __shared__ __align__(16) ushort_t Bs[16384];
    const int tid = threadIdx.x;
    const int lane = tid & 63;
    const int ln15 = lane & 15, qd = lane >> 4;
    const int wave = tid >> 6;
    const int wm = wave >> 1, wn = wave & 1;
    const int bm = blockIdx.y, bn = blockIdx.x;
    if (EPI == 4) {                      // split-K chunk
        A += (size_t)blockIdx.z * K;
        BT += (size_t)blockIdx.z * K;
    }
    // staging constants: thread covers rows rA and rA+64 of the 128-row tile,
    // granule position p=tid&3 holding source granule g = p ^ ((rA>>1)&3)
    const int rA = tid >> 2;
    const int g8 = (((tid & 3) ^ ((rA >> 1) & 3)) << 3);
    const ushort_t* Ab = A + (size_t)(bm * 128 + rA) * ld + g8;
    const ushort_t* Bb = BT + (size_t)(bn * 128 + rA) * ld + g8;
    const size_t rstep = (size_t)64 * ld;
    ushort_t* Ad = As + tid * 8;        // + slot*8192 + h*4096 (+2048 for j=1)
    ushort_t* Bd = Bs + tid * 8;

    auto stage = [&](int slot, int h, int kc) {
        const ushort_t* as = Ab + kc + h * 32;
        const ushort_t* bs = Bb + kc + h * 32;
        ushort_t* ad = Ad + slot * 8192 + h * 4096;
        ushort_t* bd = Bd + slot * 8192 + h * 4096;
        gload_lds16(as, ad);
        gload_lds16(as + rstep, ad + 2048);
        gload_lds16(bs, bd);
        gload_lds16(bs + rstep, bd + 2048);
    };

    floatx4 acc[4][4];
    #pragma unroll
    for (int i = 0; i < 4; ++i)
        #pragma unroll
        for (int j = 0; j < 4; ++j) acc[i][j] = (floatx4){0.f, 0.f, 0.f, 0.f};

    auto compute = [&](int slot, int ks) {
        short8 a[4], b[4];
        const ushort_t* ap = As + slot * 8192 + ks * 4096;
        const ushort_t* bp = Bs + slot * 8192 + ks * 4096;
        #pragma unroll
        for (int mt = 0; mt < 4; ++mt) {
            int row = wm * 64 + mt * 16 + ln15;
            a[mt] = *(const short8*)&ap[row * 32 + ((qd ^ ((row >> 1) & 3)) << 3)];
        }
        #pragma unroll
        for (int nt = 0; nt < 4; ++nt) {
            int row = wn * 64 + nt * 16 + ln15;
            b[nt] = *(const short8*)&bp[row * 32 + ((qd ^ ((row >> 1) & 3)) << 3)];
        }
        __builtin_amdgcn_s_setprio(1);
        #pragma unroll
        for (int mt = 0; mt < 4; ++mt)
            #pragma unroll
            for (int nt = 0; nt < 4; ++nt)
                acc[mt][nt] = __builtin_amdgcn_mfma_f32_16x16x32_bf16(a[mt], b[nt], acc[mt][nt], 0, 0, 0);
        __builtin_amdgcn_s_setprio(0);
    };

    const int nt = K >> 6;
    // prologue: all 4 half-units of tile 0 into slot 0
    stage(0, 0, 0);
    stage(0, 1, 0);
    // main loop: tiles 0..nt-2 with steady-state counted waits
    #pragma unroll 1
    for (int t = 0; t < nt - 1; ++t) {
        const int slot = t & 1, nslot = slot ^ 1;
        const int kn = (t + 1) << 6;
        // P0 (khalf 0)
        stage(nslot, 0, kn);
        asm volatile("s_waitcnt vmcnt(8)" ::: "memory");
        __builtin_amdgcn_s_barrier();
        __builtin_amdgcn_sched_barrier(0);
        compute(slot, 0);
        // P1 (khalf 1)
        stage(nslot, 1, kn);
        asm volatile("s_waitcnt vmcnt(8)" ::: "memory");
        __builtin_amdgcn_s_barrier();
        __builtin_amdgcn_sched_barrier(0);
        compute(slot, 1);
    }
    {   // tail tile nt-1: no prefetch, drain progressively
        const int slot = (nt - 1) & 1;
        asm volatile("s_waitcnt vmcnt(4)" ::: "memory");
        __builtin_amdgcn_s_barrier();
        __builtin_amdgcn_sched_barrier(0);
        compute(slot, 0);
        asm volatile("s_waitcnt vmcnt(0)" ::: "memory");
        __builtin_amdgcn_s_barrier();
        __builtin_amdgcn_sched_barrier(0);
        compute(slot, 1);
    }

    const int row0 = bm * 128 + wm * 64, col0 = bn * 128 + wn * 64;
    #pragma unroll
    for (int mt = 0; mt < 4; ++mt)
        #pragma unroll
        for (int nt2 = 0; nt2 < 4; ++nt2) {
            if (EPI == 0) {
                int col = col0 + nt2 * 16 + ln15;
                unsigned uc = (unsigned)col;
                unsigned hn = uc / 192u;
                unsigned j = uc - hn * 192u;
                int rowb = row0 + mt * 16 + qd * 4;
                int bb = rowb >> 11, sidx = rowb & 2047;
                if (j < 128u) {                  // Q or K -> qkv scatter (2B)
                    #pragma unroll
                    for (int r = 0; r < 4; ++r) {
                        float v = acc[mt][nt2][r];
                        if (j >= 64u) v *= KSCALE;
                        ((ushort_t*)outp)[(((size_t)bb * NH_ + hn) * S_ + sidx + r) * 192 + j] = f2bf(v);
                    }
                } else {                         // V -> vT[bh][h][s], packed 8B
                    ushort4v pk;
                    #pragma unroll
                    for (int r = 0; r < 4; ++r) pk[r] = f2bf(acc[mt][nt2][r]);
                    *(ushort4v*)&((ushort_t*)outp2)[((size_t)(bb * NH_ + hn) * HD_ + (j - 128u)) * S_ + sidx] = pk;
                }
            } else {
                #pragma unroll
                for (int r = 0; r < 4; ++r) {
                    int row = row0 + mt * 16 + qd * 4 + r;
                    int col = col0 + nt2 * 16 + ln15;
                    float v = acc[mt][nt2][r];
                    if (EPI == 1) {
                        v += bias[col];
                        // fast exact-shaped GELU: tanh form via exp2 (max err ~3e-4 << bf16 step)
                        float u = v * (0.7978845608f + 0.0356774081f * v * v);
                        float e = exp2f(fminf(u * 2.88539008f, 80.f));
                        float rc = __builtin_amdgcn_rcpf(e + 1.f);
                        float g = v * (1.f - rc);
                        ((ushort_t*)outp)[(size_t)row * N + col] = f2bf(g);
                    } else {   // EPI 4: plain fp32 partial store (no atomics)
                        ((float*)outp)[(size_t)blockIdx.z * ((size_t)B_ * S_ * D_) +
                                       (size_t)row * N + col] = v;
                    }
                }
            }
        }
}

// ---------------------------------------------------------------- flash attention (causal)
__global__ __launch_bounds__(256) void attn_kernel(const ushort_t* __restrict__ qkv,
                                                   const ushort_t* __restrict__ vT,
                                                   float* __restrict__ attn_out) {
    __shared__ __align__(16) ushort_t Ks[128 * 64];     // [key=128][hd=64], 8 gran/row swiz &7
    __shared__ __align__(16) ushort_t Vs[64 * 128];     // [hd=64][key=128], 16 gran/row swiz &15
    __shared__ __align__(16) ushort_t Ps[4][16 * 72];   // per-wave P: [q=16][key=64]
    const int tid = threadIdx.x, lane = tid & 63, w = tid >> 6;
    const int ln15 = lane & 15, qd = lane >> 4;
    const int px = blockIdx.x;                          // 0..15
    const int bh = blockIdx.z * NH_ + blockIdx.y;
    const size_t qbase = (size_t)bh * S_ * 192;
    const size_t vtbase = (size_t)bh * HD_ * S_;
    ushort_t* myP = (ushort_t*)Ps[w];

    #pragma unroll 1
    for (int pq = 0; pq < 2; ++pq) {
        const int qt = pq ? px : 31 - px;
        const int qb = qt * 64 + w * 16;

        const ushort_t* qrow = qkv + qbase + (size_t)(qb + ln15) * 192;
        short8 bq[2];
        bq[0] = *(const short8*)(qrow + qd * 8);
        bq[1] = *(const short8*)(qrow + 32 + qd * 8);

        float lcur = 0.f;
        floatx4 oacc[4];
        #pragma unroll
        for (int mt = 0; mt < 4; ++mt) oacc[mt] = (floatx4){0.f, 0.f, 0.f, 0.f};

        auto qk_half = [&](int kh, floatx4* s) {
            #pragma unroll
            for (int mt = 0; mt < 4; ++mt) s[mt] = (floatx4){0.f, 0.f, 0.f, 0.f};
            #pragma unroll
            for (int ks = 0; ks < 2; ++ks)
                #pragma unroll
                for (int mt = 0; mt < 4; ++mt) {
                    int row = kh * 64 + mt * 16 + ln15;
                    short8 ak = *(const short8*)&Ks[row * 64 + (((ks * 4 + qd) ^ (row & 7)) << 3)];
                    s[mt] = __builtin_amdgcn_mfma_f32_16x16x32_bf16(ak, bq[ks], s[mt], 0, 0, 0);
                }
        };
        auto softmax_pv = [&](floatx4* s, int kh, bool mask) {
            if (mask) {                      // causal mask on the diagonal tile
                int q = qb + ln15;
                #pragma unroll
                for (int mt = 0; mt < 4; ++mt)
                    #pragma unroll
                    for (int r = 0; r < 4; ++r)
                        if (qt * 64 + mt * 16 + qd * 4 + r > q) s[mt][r] = -1e30f;
            }
            float rsum = 0.f;
            #pragma unroll
            for (int mt = 0; mt < 4; ++mt) {
                ushort4v pk;
                #pragma unroll
                for (int r = 0; r < 4; ++r) {
                    float p = exp2f(s[mt][r]);
                    rsum += p;
                    pk[r] = (ushort_t)(__builtin_bit_cast(unsigned, p) >> 16);  // truncate
                }
                *(ushort4v*)&myP[ln15 * 72 + mt * 16 + qd * 4] = pk;   // wave-private
            }
            rsum += __shfl_xor(rsum, 16);
            rsum += __shfl_xor(rsum, 32);
            lcur += rsum;
            #pragma unroll
            for (int g2 = 0; g2 < 2; ++g2) {
                short8 bp = *(const short8*)&myP[ln15 * 72 + g2 * 32 + qd * 8];
                #pragma unroll
                for (int mt = 0; mt < 4; ++mt) {
                    int row = mt * 16 + ln15;
                    short8 av = *(const short8*)&Vs[row * 128 + (((kh * 8 + g2 * 4 + qd) ^ (row & 15)) << 3)];
                    oacc[mt] = __builtin_amdgcn_mfma_f32_16x16x32_bf16(av, bp, oacc[mt], 0, 0, 0);
                }
            }
        };

        const int ntiles = qt + 1;
        for (int kt2 = 0; kt2 < ntiles; kt2 += 2) {
            __syncthreads();
            // stage 128 keys of K and V^T (over-stage clamped on odd tail; compute skipped)
            #pragma unroll
            for (int i = 0; i < 4; ++i) {
                int gb = (i * 4 + w) * 64;              // wave-uniform granule base (of 1024)
                int g = gb + lane;
                int krow = g >> 3;
                int kcg = (g & 7) ^ (krow & 7);
                int key = kt2 * 64 + krow; if (key > S_ - 1) key = S_ - 1;
                gload_lds16(qkv + qbase + (size_t)key * 192 + 64 + kcg * 8, &Ks[gb * 8]);
                int vrow = g >> 4;
                int vcg = (g & 15) ^ (vrow & 15);
                int vkey = kt2 * 64 + vcg * 8; if (vkey > S_ - 8) vkey = S_ - 8;
                gload_lds16(vT + vtbase + (size_t)vrow * S_ + vkey, &Vs[gb * 8]);
            }
            __syncthreads();

            if (kt2 + 1 < ntiles) {          // fused pair: ILP across the two sub-rounds
                floatx4 s0[4], s1[4];
                qk_half(0, s0);
                qk_half(1, s1);
                softmax_pv(s0, 0, false);                   // kt2 < qt here, never diagonal
                softmax_pv(s1, 1, kt2 + 1 == qt);
            } else {
                floatx4 s0[4];
                qk_half(0, s0);
                softmax_pv(s0, 0, kt2 == qt);
            }
        }
        float inv = 1.f / lcur;
        int q = qb + ln15;
        #pragma unroll
        for (int mt = 0; mt < 4; ++mt) {
            floatx4 o = oacc[mt] * inv;
            *(floatx4*)&attn_out[((size_t)bh * S_ + q) * HD_ + mt * 16 + qd * 4] = o;
        }
    }
}

// ---------------------------------------------------------------- launch
extern "C" void kernel_launch(void* const* d_in, const int* in_sizes, int n_in,
                              void* d_out, int out_size, void* d_ws, size_t ws_size,
                              hipStream_t stream) {
    const float* x = (const float*)d_in[0];
    const float* W_qkv = (const float*)d_in[1];
    const float* W_out = (const float*)d_in[2];
    const float* ln1_w = (const float*)d_in[3];
    const float* ln1_b = (const float*)d_in[4];
    const float* ln2_w = (const float*)d_in[5];
    const float* ln2_b = (const float*)d_in[6];
    const float* W1 = (const float*)d_in[7];
    const float* b1 = (const float*)d_in[8];
    const float* W2 = (const float*)d_in[9];
    const float* b2 = (const float*)d_in[10];

    char* ws = (char*)d_ws;
    const size_t MB = 1024 * 1024;
    ushort_t* ln1_out = (ushort_t*)(ws + 0 * MB);      // 8 MiB
    ushort_t* WqkvT   = (ushort_t*)(ws + 8 * MB);      // 6 MiB
    ushort_t* qkv     = (ushort_t*)(ws + 14 * MB);     // 24 MiB
    ushort_t* vT      = (ushort_t*)(ws + 38 * MB);     // 8 MiB
    float*    attn_o  = (float*)(ws + 46 * MB);        // 16 MiB
    float*    x1      = (float*)(ws + 64 * MB);        // 16 MiB
    ushort_t* ln2_out = (ushort_t*)(ws + 80 * MB);     // 8 MiB
    ushort_t* W1T     = (ushort_t*)(ws + 88 * MB);     // 8 MiB
    ushort_t* hbuf    = (ushort_t*)(ws + 96 * MB);     // 32 MiB
    ushort_t* W2T     = (ushort_t*)(ws + 128 * MB);    // 8 MiB
    float*    wsum    = (float*)(ws + 136 * MB);       // 4 KiB
    // MLP2 split-K partials: 2 x 16 MiB fp32. Aliases ws[0..32 MiB]
    // (ln1_out/WqkvT/qkv) — all dead by the time MLP2 runs.
    float*    mlp2p   = (float*)(ws + 0 * MB);         // 32 MiB

    // fused prep: 704 transpose slabs + 8 wsum + 1024 LN1 blocks, all in the drain window
    prep_kernel<<<dim3(712 + 1024), 256, 0, stream>>>(
        W_qkv, W1, W2, W_out, WqkvT, W1T, W2T, wsum, x, ln1_w, ln1_b, ln1_out);
    gemm_bt<0><<<dim3(3072 / 128, (B_ * S_) / 128), 256, 0, stream>>>(
        ln1_out, WqkvT, B_ * S_, 3072, D_, D_, nullptr, qkv, vT);
    attn_kernel<<<dim3(S_ / 128, NH_, B_), 256, 0, stream>>>(qkv, vT, attn_o);
    gather_resid<<<dim3(8, 64), 256, 0, stream>>>(x, attn_o, wsum, x1);
    ln4_kernel<<<dim3(1024), 256, 0, stream>>>(x1, ln2_w, ln2_b, ln2_out);
    gemm_bt<1><<<dim3(M_ / 128, (B_ * S_) / 128), 256, 0, stream>>>(
        ln2_out, W1T, B_ * S_, M_, D_, D_, b1, hbuf, nullptr);
    // MLP2: split-K=2, plain fp32 partial stores (no atomics), then vectorized reduce
    gemm_bt<4><<<dim3(D_ / 128, (B_ * S_) / 128, 2), 256, 0, stream>>>(
        hbuf, W2T, B_ * S_, D_, M_ / 2, M_, nullptr, mlp2p, nullptr);
    mlp2_reduce<<<dim3(1024), 256, 0, stream>>>(mlp2p, x1, b2, (float*)d_out);
}

// Round 19
// 382.933 us; speedup vs baseline: 1.0270x; 1.0270x over previous
//
#include <hip/hip_runtime.h>

typedef unsigned short ushort_t;
typedef __attribute__((ext_vector_type(8))) short short8;
typedef __attribute__((ext_vector_type(4))) float floatx4;
typedef __attribute__((ext_vector_type(4))) unsigned short ushort4v;

#define B_ 2
#define S_ 2048
#define D_ 1024
#define NH_ 16
#define HD_ 64
#define M_ 4096

// 0.125 (1/sqrt(hd)) * log2(e), folded into K at the QKV epilogue
#define KSCALE 0.18033688011112042f

__device__ __forceinline__ ushort_t f2bf(float f) {
    unsigned u = __builtin_bit_cast(unsigned, f);
    return (ushort_t)((u + 0x7FFFu + ((u >> 16) & 1u)) >> 16);
}

__device__ __forceinline__ void gload_lds16(const ushort_t* g, ushort_t* l) {
    __builtin_amdgcn_global_load_lds(
        (const __attribute__((address_space(1))) unsigned int*)(g),
        (__attribute__((address_space(3))) unsigned int*)(l), 16, 0, 0);
}

__device__ __forceinline__ void waitv(int n) {
    if (n >= 12)      asm volatile("s_waitcnt vmcnt(12)" ::: "memory");
    else if (n == 8)  asm volatile("s_waitcnt vmcnt(8)" ::: "memory");
    else if (n == 4)  asm volatile("s_waitcnt vmcnt(4)" ::: "memory");
    else              asm volatile("s_waitcnt vmcnt(0)" ::: "memory");
}

// ---------------------------------------------------------------- fat transpose: 256 src rows x 64 src cols
__device__ __forceinline__ void transpose_slab(
    const float* __restrict__ src, ushort_t* __restrict__ dst,
    int srs, int drs, int by, int bx, int tid, ushort_t* L) {
    const int tx = tid & 15, ty = tid >> 4;
    const float* s0 = src + (size_t)(by * 256 + ty * 4) * srs + bx * 64 + tx * 4;
    #pragma unroll
    for (int i = 0; i < 4; ++i) {
        float a[4][4];
        #pragma unroll
        for (int r = 0; r < 4; ++r) {
            float4 m = *(const float4*)(s0 + (size_t)(i * 64 + r) * srs);
            a[r][0] = m.x; a[r][1] = m.y; a[r][2] = m.z; a[r][3] = m.w;
        }
        const int p = i * 8 + (ty >> 1), plow = ty & 1;   // granule-pair index of g = i*16+ty
        #pragma unroll
        for (int j = 0; j < 4; ++j) {
            const int c = tx * 4 + j;                     // dst-local row (= src col)
            const int pp = p ^ tx;                        // 16B-unit swizzle, s(c) = c>>2 = tx
            ushort4v t;
            t[0] = f2bf(a[0][j]); t[1] = f2bf(a[1][j]);
            t[2] = f2bf(a[2][j]); t[3] = f2bf(a[3][j]);
            *(ushort4v*)&L[c * 256 + (pp * 2 + plow) * 4] = t;
        }
    }
    __syncthreads();
    const int k = tid & 31, cg = tid >> 5;
    #pragma unroll
    for (int it = 0; it < 8; ++it) {
        const int c = it * 8 + cg;
        const int pp = k ^ (c >> 2);                      // inverse of the write swizzle
        *(short8*)(dst + (size_t)(bx * 64 + c) * drs + by * 256 + k * 8) =
            *(const short8*)&L[c * 256 + pp * 8];
    }
}

// ---------------------------------------------------------------- LayerNorm (ddof=1): one row per WAVE, barrier-free
__device__ __forceinline__ void ln_row_wave(const float* __restrict__ x,
                                            const float* __restrict__ w,
                                            const float* __restrict__ b,
                                            ushort_t* __restrict__ out, int row, int l) {
    const float* xr = x + (size_t)row * D_;
    float4 v[4]; float s = 0.f, ss = 0.f;
    #pragma unroll
    for (int i = 0; i < 4; ++i) {
        v[i] = *(const float4*)(xr + (i * 64 + l) * 4);
        s += v[i].x + v[i].y + v[i].z + v[i].w;
        ss += v[i].x * v[i].x + v[i].y * v[i].y + v[i].z * v[i].z + v[i].w * v[i].w;
    }
    #pragma unroll
    for (int off = 32; off >= 1; off >>= 1) { s += __shfl_xor(s, off); ss += __shfl_xor(ss, off); }
    float mu = s * (1.f / D_);
    float var = (ss - (float)D_ * mu * mu) * (1.f / (D_ - 1));
    float rstd = rsqrtf(var + 1e-4f);
    #pragma unroll
    for (int i = 0; i < 4; ++i) {
        int d = (i * 64 + l) * 4;
        float4 wv = *(const float4*)(w + d);
        float4 bv = *(const float4*)(b + d);
        ushort4v o;
        o[0] = f2bf((v[i].x - mu) * rstd * wv.x + bv.x);
        o[1] = f2bf((v[i].y - mu) * rstd * wv.y + bv.y);
        o[2] = f2bf((v[i].z - mu) * rstd * wv.z + bv.z);
        o[3] = f2bf((v[i].w - mu) * rstd * wv.w + bv.w);
        *(ushort4v*)&out[(size_t)row * D_ + d] = o;
    }
}

__global__ __launch_bounds__(256) void ln4_kernel(const float* __restrict__ x,
                                                  const float* __restrict__ w,
                                                  const float* __restrict__ b,
                                                  ushort_t* __restrict__ out) {
    ln_row_wave(x, w, b, out, blockIdx.x * 4 + (threadIdx.x >> 6), threadIdx.x & 63);
}

// ---------------------------------------------------------------- fused prep: ALL transposes + wsum + LN1
__global__ __launch_bounds__(256) void prep_kernel(
    const float* __restrict__ W_qkv, const float* __restrict__ W1,
    const float* __restrict__ W2, const float* __restrict__ W_out,
    ushort_t* __restrict__ WqkvT, ushort_t* __restrict__ W1T,
    ushort_t* __restrict__ W2T, float* __restrict__ wsum,
    const float* __restrict__ x, const float* __restrict__ ln1_w,
    const float* __restrict__ ln1_b, ushort_t* __restrict__ ln1_out) {
    __shared__ __align__(16) ushort_t L[64 * 256];      // 32 KiB
    const int bid = blockIdx.x;
    const int tid = threadIdx.x;
    if (bid < 192) {                    // W_qkv [16][1024][192] -> WqkvT [16*192][1024]
        int bz = bid / 12, rem = bid % 12;
        transpose_slab(W_qkv + (size_t)bz * D_ * 192, WqkvT + (size_t)bz * 192 * D_,
                       192, D_, rem / 3, rem % 3, tid, L);
    } else if (bid < 448) {             // W1 [1024][4096] -> W1T [4096][1024]
        int r = bid - 192;
        transpose_slab(W1, W1T, M_, D_, r >> 6, r & 63, tid, L);
    } else if (bid < 704) {             // W2 [4096][1024] -> W2T [1024][4096]
        int r = bid - 448;
        transpose_slab(W2, W2T, D_, M_, r >> 4, r & 15, tid, L);
    } else if (bid < 712) {             // wsum over (n,h) of W_out, float4 lanes
        int cb = bid - 704;
        float4* part = (float4*)L;
        int tx = tid & 31, rg = tid >> 5;
        int col = cb * 128 + tx * 4;
        float4 s = {0.f, 0.f, 0.f, 0.f};
        for (int r = rg; r < NH_ * HD_; r += 8) {
            float4 v = *(const float4*)(W_out + (size_t)r * D_ + col);
            s.x += v.x; s.y += v.y; s.z += v.z; s.w += v.w;
        }
        part[tid] = s;
        __syncthreads();
        if (tid < 32) {
            float4 t = {0.f, 0.f, 0.f, 0.f};
            #pragma unroll
            for (int g = 0; g < 8; ++g) {
                float4 p = part[g * 32 + tid];
                t.x += p.x; t.y += p.y; t.z += p.z; t.w += p.w;
            }
            *(float4*)(wsum + cb * 128 + tid * 4) = t;
        }
    } else {                            // LN1: 4 rows per block, one per wave
        ln_row_wave(x, ln1_w, ln1_b, ln1_out, (bid - 712) * 4 + (tid >> 6), tid & 63);
    }
}

// ---------------------------------------------------------------- gather + residual (x1 only; d_out handled by mlp2_reduce)
__global__ __launch_bounds__(256) void gather_resid(
    const float* __restrict__ x, const float* __restrict__ attn,
    const float* __restrict__ wsum, float* __restrict__ x1) {
    __shared__ float tile[128][65];
    const int tid = threadIdx.x;
    const int dchunk = blockIdx.x;          // 8 chunks of 128 d
    const int stile = blockIdx.y;           // 64 tiles: b = stile>>5, shi = stile&31
    const int b = stile >> 5, shi = stile & 31;
    const int h = tid & 63;
    const int wv = tid >> 6;
    #pragma unroll
    for (int r = 0; r < 32; ++r) {
        int dloc = r * 4 + wv;
        int d = dchunk * 128 + dloc;
        int q = ((d & 63) << 5) + shi;
        tile[dloc][h] = attn[((size_t)(b * NH_ + (d >> 6)) * S_ + q) * HD_ + h];
    }
    __syncthreads();
    const int row0 = b * S_ + shi * 64;
    const int dcol = tid & 127;
    const int d = dchunk * 128 + dcol;
    const float wsd = wsum[d];
    #pragma unroll
    for (int r = 0; r < 32; ++r) {
        int sr = r * 2 + (tid >> 7);
        size_t idx = (size_t)(row0 + sr) * D_ + d;
        x1[idx] = x[idx] + wsd * tile[dcol][sr];
    }
}

// ---------------------------------------------------------------- MLP2 split-K reduce: out = x1 + b2 + sum_z part_z (z=4)
__global__ __launch_bounds__(256) void mlp2_reduce(
    const float* __restrict__ part, const float* __restrict__ x1,
    const float* __restrict__ b2, float* __restrict__ out) {
    int i = blockIdx.x * 256 + threadIdx.x;          // float4 index
    #pragma unroll
    for (int it = 0; it < 4; ++it, i += 1024 * 256) {
        size_t o = (size_t)i * 4;
        float4 s = *(const float4*)(x1 + o);
        float4 bb = *(const float4*)(b2 + ((i * 4) & (D_ - 1)));
        s.x += bb.x; s.y += bb.y; s.z += bb.z; s.w += bb.w;
        #pragma unroll
        for (int z = 0; z < 4; ++z) {
            float4 p = *(const float4*)(part + (size_t)z * ((size_t)B_ * S_ * D_) + o);
            s.x += p.x; s.y += p.y; s.z += p.z; s.w += p.w;
        }
        *(float4*)(out + o) = s;
    }
}

// ---------------------------------------------------------------- 256x256 GEMM, 8 waves, BK=128, 4-phase counted-vmcnt pipeline
// LDS: 4 k-slice buffers per operand (slice s of every K-tile lives in buffer s).
// Staging runs 3 stage-positions ahead of consumption -> steady-state vmcnt(12).
// Layout per buffer: [128 rowpair][8 pos x 16B]; pos = ((row&1)*4 + kgran) ^ (rowpair&7)
// -> zero-conflict ds_read_b128, linear wave writes for global_load_lds.
// EPI 0: Q/K scatter + V pack. EPI 1: fast-gelu bf16. EPI 4: split-K fp32 partial.
template <int EPI>
__global__ __launch_bounds__(512, 2) void gemm256(
    const ushort_t* __restrict__ A, const ushort_t* __restrict__ BT,
    int M, int N, int K, int ld, const float* __restrict__ bias,
    void* __restrict__ outp, void* __restrict__ outp2) {
    __shared__ __align__(16) ushort_t Abuf[4 * 8192];   // 64 KiB
    __shared__ __align__(16) ushort_t Bbuf[4 * 8192];   // 64 KiB
    const int tid = threadIdx.x;
    const int lane = tid & 63;
    const int ln15 = lane & 15, qd = lane >> 4;
    const int wave = tid >> 6;
    const int wm = wave >> 2, wn = wave & 3;            // 2 x 4 wave grid
    const int bm = blockIdx.y, bn = blockIdx.x;
    if (EPI == 4) {                      // split-K chunk
        A += (size_t)blockIdx.z * K;
        BT += (size_t)blockIdx.z * K;
    }

    // staging geometry: load l in {0,1}: granule gi = l*512 + tid of a 16KB slice buffer
    const int gi0 = tid, gi1 = 512 + tid;
    const int rp0 = gi0 >> 3, x0 = (gi0 & 7) ^ (rp0 & 7);
    const int rp1 = gi1 >> 3, x1 = (gi1 & 7) ^ (rp1 & 7);
    const int r0 = rp0 * 2 + (x0 >> 2), g0 = x0 & 3;
    const int r1 = rp1 * 2 + (x1 >> 2), g1 = x1 & 3;
    const ushort_t* As0 = A + (size_t)(bm * 256 + r0) * ld + g0 * 8;
    const ushort_t* As1 = A + (size_t)(bm * 256 + r1) * ld + g1 * 8;
    const ushort_t* Bs0 = BT + (size_t)(bn * 256 + r0) * ld + g0 * 8;
    const ushort_t* Bs1 = BT + (size_t)(bn * 256 + r1) * ld + g1 * 8;
    ushort_t* Ad0 = Abuf + gi0 * 8;  ushort_t* Ad1 = Abuf + gi1 * 8;
    ushort_t* Bd0 = Bbuf + gi0 * 8;  ushort_t* Bd1 = Bbuf + gi1 * 8;

    auto stage = [&](int sp) {           // stage position sp: tile sp>>2, slice (= buffer) sp&3
        const int koff = (sp >> 2) * 128 + (sp & 3) * 32;
        const int boff = (sp & 3) * 8192;
        gload_lds16(As0 + koff, Ad0 + boff);
        gload_lds16(As1 + koff, Ad1 + boff);
        gload_lds16(Bs0 + koff, Bd0 + boff);
        gload_lds16(Bs1 + koff, Bd1 + boff);
    };

    floatx4 acc[8][4];
    #pragma unroll
    for (int i = 0; i < 8; ++i)
        #pragma unroll
        for (int j = 0; j < 4; ++j) acc[i][j] = (floatx4){0.f, 0.f, 0.f, 0.f};

    auto frag = [&](const ushort_t* buf, int row) -> short8 {
        int rp = row >> 1;
        int pos = (((row & 1) << 2) | qd) ^ (rp & 7);
        return *(const short8*)&buf[rp * 64 + pos * 8];
    };

    auto compute = [&](int sb) {         // one k-slice (32 k): 32 MFMA
        const ushort_t* ap = Abuf + sb * 8192;
        const ushort_t* bp = Bbuf + sb * 8192;
        short8 a[8], b[4];
        #pragma unroll
        for (int m = 0; m < 8; ++m) a[m] = frag(ap, wm * 128 + m * 16 + ln15);
        #pragma unroll
        for (int n = 0; n < 4; ++n) b[n] = frag(bp, wn * 64 + n * 16 + ln15);
        __builtin_amdgcn_s_setprio(1);
        #pragma unroll
        for (int m = 0; m < 8; ++m)
            #pragma unroll
            for (int n = 0; n < 4; ++n)
                acc[m][n] = __builtin_amdgcn_mfma_f32_16x16x32_bf16(a[m], b[n], acc[m][n], 0, 0, 0);
        __builtin_amdgcn_s_setprio(0);
    };

    const int NT = K >> 7;               // K-tiles of 128
    const int last = 4 * NT - 1;
    stage(0); stage(1); stage(2);        // prologue: 3 positions ahead
    #pragma unroll 1
    for (int t = 0; t < NT; ++t) {
        #pragma unroll
        for (int q = 0; q < 4; ++q) {
            const int ph = t * 4 + q;
            const int sp = ph + 3;
            if (sp <= last) stage(sp);
            const int rem = last - ph;
            waitv(rem >= 3 ? 12 : rem * 4);
            __builtin_amdgcn_s_barrier();
            __builtin_amdgcn_sched_barrier(0);
            compute(q);
            __builtin_amdgcn_sched_barrier(0);
            __builtin_amdgcn_s_barrier();
            __builtin_amdgcn_sched_barrier(0);
        }
    }

    const int row0 = bm * 256 + wm * 128, col0 = bn * 256 + wn * 64;
    #pragma unroll
    for (int m = 0; m < 8; ++m)
        #pragma unroll
        for (int n = 0; n < 4; ++n) {
            if (EPI == 0) {
                int col = col0 + n * 16 + ln15;
                unsigned uc = (unsigned)col;
                unsigned hn = uc / 192u;
                unsigned j = uc - hn * 192u;
                int rowb = row0 + m * 16 + qd * 4;
                int bb = rowb >> 11, sidx = rowb & 2047;
                if (j < 128u) {                  // Q or K -> qkv scatter (2B)
                    #pragma unroll
                    for (int r = 0; r < 4; ++r) {
                        float v = acc[m][n][r];
                        if (j >= 64u) v *= KSCALE;
                        ((ushort_t*)outp)[(((size_t)bb * NH_ + hn) * S_ + sidx + r) * 192 + j] = f2bf(v);
                    }
                } else {                         // V -> vT[bh][h][s], packed 8B
                    ushort4v pk;
                    #pragma unroll
                    for (int r = 0; r < 4; ++r) pk[r] = f2bf(acc[m][n][r]);
                    *(ushort4v*)&((ushort_t*)outp2)[((size_t)(bb * NH_ + hn) * HD_ + (j - 128u)) * S_ + sidx] = pk;
                }
            } else {
                #pragma unroll
                for (int r = 0; r < 4; ++r) {
                    int row = row0 + m * 16 + qd * 4 + r;
                    int col = col0 + n * 16 + ln15;
                    float v = acc[m][n][r];
                    if (EPI == 1) {
                        v += bias[col];
                        // fast exact-shaped GELU: tanh form via exp2 (max err ~3e-4 << bf16 step)
                        float u = v * (0.7978845608f + 0.0356774081f * v * v);
                        float e = exp2f(fminf(u * 2.88539008f, 80.f));
                        float rc = __builtin_amdgcn_rcpf(e + 1.f);
                        float g = v * (1.f - rc);
                        ((ushort_t*)outp)[(size_t)row * N + col] = f2bf(g);
                    } else {   // EPI 4: plain fp32 partial store (no atomics)
                        ((float*)outp)[(size_t)blockIdx.z * ((size_t)B_ * S_ * D_) +
                                       (size_t)row * N + col] = v;
                    }
                }
            }
        }
}

// ---------------------------------------------------------------- flash attention (causal)
__global__ __launch_bounds__(256) void attn_kernel(const ushort_t* __restrict__ qkv,
                                                   const ushort_t* __restrict__ vT,
                                                   float* __restrict__ attn_out) {
    __shared__ __align__(16) ushort_t Ks[128 * 64];     // [key=128][hd=64], 8 gran/row swiz &7
    __shared__ __align__(16) ushort_t Vs[64 * 128];     // [hd=64][key=128], 16 gran/row swiz &15
    __shared__ __align__(16) ushort_t Ps[4][16 * 72];   // per-wave P: [q=16][key=64]
    const int tid = threadIdx.x, lane = tid & 63, w = tid >> 6;
    const int ln15 = lane & 15, qd = lane >> 4;
    const int px = blockIdx.x;                          // 0..15
    const int bh = blockIdx.z * NH_ + blockIdx.y;
    const size_t qbase = (size_t)bh * S_ * 192;
    const size_t vtbase = (size_t)bh * HD_ * S_;
    ushort_t* myP = (ushort_t*)Ps[w];

    #pragma unroll 1
    for (int pq = 0; pq < 2; ++pq) {
        const int qt = pq ? px : 31 - px;
        const int qb = qt * 64 + w * 16;

        const ushort_t* qrow = qkv + qbase + (size_t)(qb + ln15) * 192;
        short8 bq[2];
        bq[0] = *(const short8*)(qrow + qd * 8);
        bq[1] = *(const short8*)(qrow + 32 + qd * 8);

        float lcur = 0.f;
        floatx4 oacc[4];
        #pragma unroll
        for (int mt = 0; mt < 4; ++mt) oacc[mt] = (floatx4){0.f, 0.f, 0.f, 0.f};

        auto qk_half = [&](int kh, floatx4* s) {
            #pragma unroll
            for (int mt = 0; mt < 4; ++mt) s[mt] = (floatx4){0.f, 0.f, 0.f, 0.f};
            #pragma unroll
            for (int ks = 0; ks < 2; ++ks)
                #pragma unroll
                for (int mt = 0; mt < 4; ++mt) {
                    int row = kh * 64 + mt * 16 + ln15;
                    short8 ak = *(const short8*)&Ks[row * 64 + (((ks * 4 + qd) ^ (row & 7)) << 3)];
                    s[mt] = __builtin_amdgcn_mfma_f32_16x16x32_bf16(ak, bq[ks], s[mt], 0, 0, 0);
                }
        };
        auto softmax_pv = [&](floatx4* s, int kh, bool mask) {
            if (mask) {                      // causal mask on the diagonal tile
                int q = qb + ln15;
                #pragma unroll
                for (int mt = 0; mt < 4; ++mt)
                    #pragma unroll
                    for (int r = 0; r < 4; ++r)
                        if (qt * 64 + mt * 16 + qd * 4 + r > q) s[mt][r] = -1e30f;
            }
            float rsum = 0.f;
            #pragma unroll
            for (int mt = 0; mt < 4; ++mt) {
                ushort4v pk;
                #pragma unroll
                for (int r = 0; r < 4; ++r) {
                    float p = exp2f(s[mt][r]);
                    rsum += p;
                    pk[r] = (ushort_t)(__builtin_bit_cast(unsigned, p) >> 16);  // truncate
                }
                *(ushort4v*)&myP[ln15 * 72 + mt * 16 + qd * 4] = pk;   // wave-private
            }
            rsum += __shfl_xor(rsum, 16);
            rsum += __shfl_xor(rsum, 32);
            lcur += rsum;
            #pragma unroll
            for (int g2 = 0; g2 < 2; ++g2) {
                short8 bp = *(const short8*)&myP[ln15 * 72 + g2 * 32 + qd * 8];
                #pragma unroll
                for (int mt = 0; mt < 4; ++mt) {
                    int row = mt * 16 + ln15;
                    short8 av = *(const short8*)&Vs[row * 128 + (((kh * 8 + g2 * 4 + qd) ^ (row & 15)) << 3)];
                    oacc[mt] = __builtin_amdgcn_mfma_f32_16x16x32_bf16(av, bp, oacc[mt], 0, 0, 0);
                }
            }
        };

        const int ntiles = qt + 1;
        for (int kt2 = 0; kt2 < ntiles; kt2 += 2) {
            __syncthreads();
            // stage 128 keys of K and V^T (over-stage clamped on odd tail; compute skipped)
            #pragma unroll
            for (int i = 0; i < 4; ++i) {
                int gb = (i * 4 + w) * 64;              // wave-uniform granule base (of 1024)
                int g = gb + lane;
                int krow = g >> 3;
                int kcg = (g & 7) ^ (krow & 7);
                int key = kt2 * 64 + krow; if (key > S_ - 1) key = S_ - 1;
                gload_lds16(qkv + qbase + (size_t)key * 192 + 64 + kcg * 8, &Ks[gb * 8]);
                int vrow = g >> 4;
                int vcg = (g & 15) ^ (vrow & 15);
                int vkey = kt2 * 64 + vcg * 8; if (vkey > S_ - 8) vkey = S_ - 8;
                gload_lds16(vT + vtbase + (size_t)vrow * S_ + vkey, &Vs[gb * 8]);
            }
            __syncthreads();

            if (kt2 + 1 < ntiles) {          // fused pair: ILP across the two sub-rounds
                floatx4 s0[4], s1[4];
                qk_half(0, s0);
                qk_half(1, s1);
                softmax_pv(s0, 0, false);                   // kt2 < qt here, never diagonal
                softmax_pv(s1, 1, kt2 + 1 == qt);
            } else {
                floatx4 s0[4];
                qk_half(0, s0);
                softmax_pv(s0, 0, kt2 == qt);
            }
        }
        float inv = 1.f / lcur;
        int q = qb + ln15;
        #pragma unroll
        for (int mt = 0; mt < 4; ++mt) {
            floatx4 o = oacc[mt] * inv;
            *(floatx4*)&attn_out[((size_t)bh * S_ + q) * HD_ + mt * 16 + qd * 4] = o;
        }
    }
}

// ---------------------------------------------------------------- launch
extern "C" void kernel_launch(void* const* d_in, const int* in_sizes, int n_in,
                              void* d_out, int out_size, void* d_ws, size_t ws_size,
                              hipStream_t stream) {
    const float* x = (const float*)d_in[0];
    const float* W_qkv = (const float*)d_in[1];
    const float* W_out = (const float*)d_in[2];
    const float* ln1_w = (const float*)d_in[3];
    const float* ln1_b = (const float*)d_in[4];
    const float* ln2_w = (const float*)d_in[5];
    const float* ln2_b = (const float*)d_in[6];
    const float* W1 = (const float*)d_in[7];
    const float* b1 = (const float*)d_in[8];
    const float* W2 = (const float*)d_in[9];
    const float* b2 = (const float*)d_in[10];

    char* ws = (char*)d_ws;
    const size_t MB = 1024 * 1024;
    ushort_t* ln1_out = (ushort_t*)(ws + 0 * MB);      // 8 MiB
    ushort_t* WqkvT   = (ushort_t*)(ws + 8 * MB);      // 6 MiB
    ushort_t* qkv     = (ushort_t*)(ws + 14 * MB);     // 24 MiB
    ushort_t* vT      = (ushort_t*)(ws + 38 * MB);     // 8 MiB
    float*    attn_o  = (float*)(ws + 46 * MB);        // 16 MiB
    float*    x1      = (float*)(ws + 64 * MB);        // 16 MiB
    ushort_t* ln2_out = (ushort_t*)(ws + 80 * MB);     // 8 MiB
    ushort_t* W1T     = (ushort_t*)(ws + 88 * MB);     // 8 MiB
    ushort_t* hbuf    = (ushort_t*)(ws + 96 * MB);     // 32 MiB
    ushort_t* W2T     = (ushort_t*)(ws + 128 * MB);    // 8 MiB
    float*    wsum    = (float*)(ws + 136 * MB);       // 4 KiB
    // MLP2 split-K partials: 4 x 16 MiB fp32. Aliases ws[0..64 MiB]
    // (ln1_out/WqkvT/qkv/vT/attn_o) — all dead by the time MLP2 runs.
    float*    mlp2p   = (float*)(ws + 0 * MB);         // 64 MiB

    // fused prep: 704 transpose slabs + 8 wsum + 1024 LN1 blocks, all in the drain window
    prep_kernel<<<dim3(712 + 1024), 256, 0, stream>>>(
        W_qkv, W1, W2, W_out, WqkvT, W1T, W2T, wsum, x, ln1_w, ln1_b, ln1_out);
    gemm256<0><<<dim3(3072 / 256, (B_ * S_) / 256), 512, 0, stream>>>(
        ln1_out, WqkvT, B_ * S_, 3072, D_, D_, nullptr, qkv, vT);
    attn_kernel<<<dim3(S_ / 128, NH_, B_), 256, 0, stream>>>(qkv, vT, attn_o);
    gather_resid<<<dim3(8, 64), 256, 0, stream>>>(x, attn_o, wsum, x1);
    ln4_kernel<<<dim3(1024), 256, 0, stream>>>(x1, ln2_w, ln2_b, ln2_out);
    gemm256<1><<<dim3(M_ / 256, (B_ * S_) / 256), 512, 0, stream>>>(
        ln2_out, W1T, B_ * S_, M_, D_, D_, b1, hbuf, nullptr);
    // MLP2: split-K=4, plain fp32 partial stores, then vectorized reduce
    gemm256<4><<<dim3(D_ / 256, (B_ * S_) / 256, 4), 512, 0, stream>>>(
        hbuf, W2T, B_ * S_, D_, M_ / 4, M_, nullptr, mlp2p, nullptr);
    mlp2_reduce<<<dim3(1024), 256, 0, stream>>>(mlp2p, x1, b2, (float*)d_out);
}